// Round 7
// baseline (460.022 us; speedup 1.0000x reference)
//
#include <hip/hip_runtime.h>

typedef unsigned short u16;
typedef __attribute__((ext_vector_type(8))) __bf16 bf16x8;
typedef __attribute__((ext_vector_type(8))) unsigned short u16x8;
typedef __attribute__((ext_vector_type(4))) unsigned short u16x4;
typedef __attribute__((ext_vector_type(4))) float f32x4;

#define BM 256
#define BN 256
#define BK 64   // K-step per LDS buffer; double-buffered (128 KiB total)

__device__ __forceinline__ float bf2f(u16 x) {
  union { unsigned int u; float f; } un;
  un.u = ((unsigned int)x) << 16;
  return un.f;
}

__device__ __forceinline__ u16 f2bf(float f) {
  union { float f; unsigned int u; } un;
  un.f = f;
  unsigned int r = un.u + 0x7fffu + ((un.u >> 16) & 1u);
  return (u16)(r >> 16);
}

__device__ __forceinline__ void cstore(u16* p, float v)   { *p = f2bf(v); }
__device__ __forceinline__ void cstore(float* p, float v) { *p = v; }

// async global->LDS, 16B per lane; lds dst is wave-uniform base (HW adds lane*16B)
__device__ __forceinline__ void async_ld16(const u16* g, u16* l) {
  __builtin_amdgcn_global_load_lds(
      (const __attribute__((address_space(1))) unsigned int*)g,
      (__attribute__((address_space(3))) unsigned int*)l, 16, 0, 0);
}

__device__ __forceinline__ bf16x8 ldfrag(const u16* p) {
  union { u16x8 u; bf16x8 b; } c;
  c.u = *(const u16x8*)p;
  return c.b;
}

// ---------------- fp32 -> bf16 elementwise (x), 4 elems/thread ----------------
__global__ __launch_bounds__(256)
void f32_to_bf16(const float* __restrict__ s, u16* __restrict__ d)
{
  const int i = blockIdx.x * 256 + threadIdx.x;
  const float4 v = ((const float4*)s)[i];
  u16x4 o;
  o.x = f2bf(v.x); o.y = f2bf(v.y); o.z = f2bf(v.z); o.w = f2bf(v.w);
  ((u16x4*)d)[i] = o;
}

// ---------------- fp32 [R][CC] -> bf16 transposed [CC][R] ----------------
__global__ __launch_bounds__(256)
void transpose_f2b(const float* __restrict__ src, int sld,
                   u16* __restrict__ dst, int dld)
{
  __shared__ float tile[32][33];
  const int c0 = blockIdx.x * 32;
  const int r0 = blockIdx.y * 32;
  const int tx = threadIdx.x;   // 0..31
  const int ty = threadIdx.y;   // 0..7
#pragma unroll
  for (int i = ty; i < 32; i += 8)
    tile[i][tx] = src[(long long)(r0 + i) * sld + c0 + tx];
  __syncthreads();
#pragma unroll
  for (int i = ty; i < 32; i += 8)
    dst[(long long)(c0 + i) * dld + r0 + tx] = f2bf(tile[tx][i]);
}

// C[M][N] = A[M][K] * Bt[N][K]^T  (NT GEMM), bf16 in, fp32 accum, OT out.
// 256x256 tile, BK=64 double-buffered (128 KiB LDS), 8 waves (2M x 4N,
// 128x64 out/wave), 4 phases/K-tile, 16 MFMA each.
// r7: EXACT m201 per-phase rhythm — each phase issues ONLY its own frag
// reads (8 or 4 ds_read_b128) at the top, then {barrier; lgkmcnt(0)+
// sched_barrier(0); setprio(1); 16 MFMA; setprio(0); barrier}. Overlap
// comes from barrier-stagger: a wave's reads are served by the LDS pipe
// while OTHER waves finish the previous MFMA phase, so the post-barrier
// lgkmcnt(0) is ~free. B-frags (bv0/bv1) are read once (P1/P2) and reused
// in P3/P4.
// Staging ledger (r5 deep-slack, unchanged):
//   P1 top: issue B01,B23,A01 of tile j+1   (6 loads)
//   P3 top: issue A23 of tile j+1            (2 loads)
//   end-P2: vmcnt(6) -> A23 of tile j landed (issued P3 of j-1, 3-ph slack)
//   end-P4: vmcnt(2) -> B01,B23,A01 of tile j+1 landed (3-ph slack)
// LDS bank swizzle (slot ^= row&7 on 16B slots), both-sides rule: linear
// global_load_lds dest + inverse-permuted global src + XOR'd ds_read.
// T1 XCD swizzle: flat block id chunked (bijective since all grids %8==0).
// mode 0: plain; mode 1: causal skip; mode 2: K trimmed to (bx+1)*BM;
// mode 3: plain, swapped block decode. kEnd must be a multiple of 64.
// vdst != nullptr: blocks with N-base >= 2048 write u16 output TRANSPOSED
// into vdst[b][col-2048][row%2048] (fused V-transpose for the kqv GEMM).
template <typename OT>
__global__ __launch_bounds__(512, 2)
void gemm_nt(const u16* __restrict__ A, int lda, long long sA,
             const u16* __restrict__ Bt, int ldb, long long sB,
             OT* __restrict__ Cp, int ldc, long long sC,
             int K, const float* __restrict__ bias, float scale, int mode,
             u16* __restrict__ vdst)
{
  // ---- T1: XCD-chunked bijective block swizzle (requires nwg % 8 == 0) ----
  const int gx = gridDim.x, gy = gridDim.y;
  const int nwg  = gx * gy * gridDim.z;
  const int flat = blockIdx.x + gx * (blockIdx.y + gy * blockIdx.z);
  const int qch  = nwg >> 3;
  const int swzf = (flat & 7) * qch + (flat >> 3);
  int bx = swzf % gx;
  const int rem = swzf / gx;
  int by = rem % gy;
  const int bz = rem / gy;
  if (mode == 3) { const int t2 = bx; bx = by; by = t2; }
  if (mode == 1 && by > bx) return;
  A  += (long long)bz * sA;
  Bt += (long long)bz * sB;
  Cp += (long long)bz * sC;
  int kEnd = K;
  if (mode == 2) { int ke = (bx + 1) * BM; kEnd = ke < K ? ke : K; }

  __shared__ __align__(16) u16 As[2][BM * BK];
  __shared__ __align__(16) u16 Bs[2][BM * BK];

  const int tid  = threadIdx.x;
  const int wave = tid >> 6;      // 0..7
  const int lane = tid & 63;
  const int l16  = lane & 15;
  const int quad = lane >> 4;     // 0..3
  const int wm = wave >> 2;       // 0..1 -> rows wm*128..+127
  const int wn = wave & 3;        // 0..3 -> cols wn*64..+63

  // ds_read slot (16B units) = (kk*4+quad) ^ (row&7); row&7 == l16&7.
  const int sk0 = ((quad    ) ^ (l16 & 7)) * 8;   // kk = 0
  const int sk1 = ((quad + 4) ^ (l16 & 7)) * 8;   // kk = 1
  const int arow = wm * 128 + l16;
  const int brow = wn * 64  + l16;

  // staging: chunk = 1 KiB = 8 rows x 64 cols; lane l -> row chunk*8+(l>>3),
  // slot l&7; source col = swizzle-inverse ((l&7)^(l>>3))*8 elems.
  const int srow8 = lane >> 3;
  const int sx    = ((lane & 7) ^ srow8) * 8;

  // wave w stages B chunks {4w..4w+3}; A chunks: first-half {f0,f0+1},
  // second-half {f0+8,f0+9}.
  const int f0 = (wave < 4) ? (2 * wave) : (16 + 2 * (wave - 4));
  const int aCh[4] = { f0, f0 + 1, f0 + 8, f0 + 9 };

  const u16* Bgp[4];
#pragma unroll
  for (int p = 0; p < 4; ++p)
    Bgp[p] = Bt + (long long)(by * BN + (4 * wave + p) * 8 + srow8) * ldb + sx;
  const u16* Agp[4];
#pragma unroll
  for (int q = 0; q < 4; ++q)
    Agp[q] = A + (long long)(bx * BM + aCh[q] * 8 + srow8) * lda + sx;

  f32x4 zero4;
  zero4.x = zero4.y = zero4.z = zero4.w = 0.0f;
  f32x4 acc[8][4];
#pragma unroll
  for (int i = 0; i < 8; ++i)
#pragma unroll
    for (int j = 0; j < 4; ++j) acc[i][j] = zero4;

  const int nt = kEnd / BK;

  // prologue: tile 0 -> buf 0; order B0-3, A01, A23 (A23 newest — matches
  // steady-state invariant); vmcnt(2) leaves A23 in flight (landed by
  // end-P2's vmcnt(6)).
#pragma unroll
  for (int p = 0; p < 4; ++p) async_ld16(Bgp[p], &Bs[0][(4 * wave + p) * 512]);
#pragma unroll
  for (int q = 0; q < 4; ++q) async_ld16(Agp[q], &As[0][aCh[q] * 512]);
  asm volatile("s_waitcnt vmcnt(2)" ::: "memory");
  __builtin_amdgcn_s_barrier();

  for (int j = 0; j < nt; ++j) {
    const int cur = j & 1;
    const int nxt = cur ^ 1;
    const bool pf = (j + 1 < nt);
    const int ko = (j + 1) * BK;

    bf16x8 bv0[4], bv1[4], av[4];

    // ---- P1: reads bv0 + av(M0-3,kk0); stage B01,B23,A01 of tile j+1 ----
#pragma unroll
    for (int n = 0; n < 4; ++n) bv0[n] = ldfrag(&Bs[cur][(brow + n * 16) * BK + sk0]);
#pragma unroll
    for (int i = 0; i < 4; ++i) av[i]  = ldfrag(&As[cur][(arow + i * 16) * BK + sk0]);
    if (pf) {
      async_ld16(Bgp[0] + ko, &Bs[nxt][(4 * wave + 0) * 512]);
      async_ld16(Bgp[1] + ko, &Bs[nxt][(4 * wave + 1) * 512]);
      async_ld16(Bgp[2] + ko, &Bs[nxt][(4 * wave + 2) * 512]);
      async_ld16(Bgp[3] + ko, &Bs[nxt][(4 * wave + 3) * 512]);
      async_ld16(Agp[0] + ko, &As[nxt][aCh[0] * 512]);
      async_ld16(Agp[1] + ko, &As[nxt][aCh[1] * 512]);
    }
    asm volatile("" ::: "memory");
    __builtin_amdgcn_s_barrier();
    asm volatile("s_waitcnt lgkmcnt(0)" ::: "memory");
    __builtin_amdgcn_sched_barrier(0);
    __builtin_amdgcn_s_setprio(1);
#pragma unroll
    for (int i = 0; i < 4; ++i)
#pragma unroll
      for (int n = 0; n < 4; ++n)
        acc[i][n] = __builtin_amdgcn_mfma_f32_16x16x32_bf16(av[i], bv0[n], acc[i][n], 0, 0, 0);
    __builtin_amdgcn_s_setprio(0);
    asm volatile("" ::: "memory");
    __builtin_amdgcn_s_barrier();

    // ---- P2: reads bv1 + av(M0-3,kk1) ----
#pragma unroll
    for (int n = 0; n < 4; ++n) bv1[n] = ldfrag(&Bs[cur][(brow + n * 16) * BK + sk1]);
#pragma unroll
    for (int i = 0; i < 4; ++i) av[i]  = ldfrag(&As[cur][(arow + i * 16) * BK + sk1]);
    asm volatile("" ::: "memory");
    __builtin_amdgcn_s_barrier();
    asm volatile("s_waitcnt lgkmcnt(0)" ::: "memory");
    __builtin_amdgcn_sched_barrier(0);
    __builtin_amdgcn_s_setprio(1);
#pragma unroll
    for (int i = 0; i < 4; ++i)
#pragma unroll
      for (int n = 0; n < 4; ++n)
        acc[i][n] = __builtin_amdgcn_mfma_f32_16x16x32_bf16(av[i], bv1[n], acc[i][n], 0, 0, 0);
    __builtin_amdgcn_s_setprio(0);
    // A23 of tile j must land before P3-top reads (issued P3 of j-1,
    // 3-phase slack). The 6 tile-j+1 loads issued at P1 stay in flight.
    if (pf) asm volatile("s_waitcnt vmcnt(6)" ::: "memory");
    else    asm volatile("s_waitcnt vmcnt(0)" ::: "memory");
    __builtin_amdgcn_s_barrier();

    // ---- P3: reads av(M4-7,kk0), reuse bv0; stage A23 of tile j+1 ----
#pragma unroll
    for (int i = 0; i < 4; ++i) av[i] = ldfrag(&As[cur][(arow + (i + 4) * 16) * BK + sk0]);
    if (pf) {
      async_ld16(Agp[2] + ko, &As[nxt][aCh[2] * 512]);
      async_ld16(Agp[3] + ko, &As[nxt][aCh[3] * 512]);
    }
    asm volatile("" ::: "memory");
    __builtin_amdgcn_s_barrier();
    asm volatile("s_waitcnt lgkmcnt(0)" ::: "memory");
    __builtin_amdgcn_sched_barrier(0);
    __builtin_amdgcn_s_setprio(1);
#pragma unroll
    for (int i = 0; i < 4; ++i)
#pragma unroll
      for (int n = 0; n < 4; ++n)
        acc[i + 4][n] = __builtin_amdgcn_mfma_f32_16x16x32_bf16(av[i], bv0[n], acc[i + 4][n], 0, 0, 0);
    __builtin_amdgcn_s_setprio(0);
    asm volatile("" ::: "memory");
    __builtin_amdgcn_s_barrier();

    // ---- P4: reads av(M4-7,kk1), reuse bv1 ----
#pragma unroll
    for (int i = 0; i < 4; ++i) av[i] = ldfrag(&As[cur][(arow + (i + 4) * 16) * BK + sk1]);
    asm volatile("" ::: "memory");
    __builtin_amdgcn_s_barrier();
    asm volatile("s_waitcnt lgkmcnt(0)" ::: "memory");
    __builtin_amdgcn_sched_barrier(0);
    __builtin_amdgcn_s_setprio(1);
#pragma unroll
    for (int i = 0; i < 4; ++i)
#pragma unroll
      for (int n = 0; n < 4; ++n)
        acc[i + 4][n] = __builtin_amdgcn_mfma_f32_16x16x32_bf16(av[i], bv1[n], acc[i + 4][n], 0, 0, 0);
    __builtin_amdgcn_s_setprio(0);
    // B01,B23,A01 of tile j+1 must land before next P1-top reads (issued at
    // P1 of this tile, 3-phase slack). A23 (2 newest) stays in flight.
    if (pf) asm volatile("s_waitcnt vmcnt(2)" ::: "memory");
    __builtin_amdgcn_s_barrier();
  }

  // epilogue: C/D layout col = lane&15, row = quad*4 + reg (verified m89/m91)
  const bool isv = (vdst != nullptr) && (by * BN >= 2048);
  if (isv) {
    // fused V-transpose: write vdst[b][vc][t], b = batch, t = row % 2048.
    // Lane's 4 acc rows = 4 consecutive t at fixed vc -> one 8 B store.
    const int b  = bx >> 3;                       // 2048/BM = 8 blocks/batch
    const int t0 = (bx & 7) * BM + wm * 128 + quad * 4;
    u16* vb = vdst + (long long)b * 1024 * 2048;  // C * T
    const int vc0 = by * BN - 2048 + wn * 64 + l16;
#pragma unroll
    for (int j = 0; j < 4; ++j) {
      const int vc = vc0 + j * 16;
      const float bval = bias ? bias[2048 + vc] : 0.0f;
#pragma unroll
      for (int i = 0; i < 8; ++i) {
        u16x4 o;
#pragma unroll
        for (int r = 0; r < 4; ++r) o[r] = f2bf(acc[i][j][r] * scale + bval);
        *(u16x4*)(vb + (long long)vc * 2048 + t0 + i * 16) = o;
      }
    }
  } else {
    const long long row0 = (long long)bx * BM + wm * 128 + quad * 4;
    const int col0 = by * BN + wn * 64 + l16;
#pragma unroll
    for (int j = 0; j < 4; ++j) {
      const int col = col0 + j * 16;
      const float bval = bias ? bias[col] : 0.0f;
#pragma unroll
      for (int i = 0; i < 8; ++i) {
#pragma unroll
        for (int r = 0; r < 4; ++r) {
          const long long row = row0 + i * 16 + r;
          cstore(&Cp[row * ldc + col], acc[i][j][r] * scale + bval);
        }
      }
    }
  }
}

// causal softmax over one row of [T] bf16 scores, in place.
// Thread t owns elements [8t, 8t+8). Reads AND writes only [0, Lw),
// Lw = ceil(L/256)*256 — exactly the range the K-trimmed PV GEMM consumes.
// requires T == 2048
__global__ __launch_bounds__(256)
void softmax_causal(u16* __restrict__ sc, int T)
{
  const int row = blockIdx.x;       // z*T + t
  const int t = row & (T - 1);
  u16* p = sc + (long long)row * T;
  const int L  = t + 1;
  const int Lw = ((t >> 8) + 1) << 8;   // 256-aligned for BM=256 PV trim
  const int tid = threadIdx.x;
  const int lane = tid & 63;
  const int wave = tid >> 6;
  const int base = tid * 8;

  float v[8];
  float m = -1e30f;
  if (base < Lw) {
    const u16x8 in = *(const u16x8*)(p + base);
#pragma unroll
    for (int e = 0; e < 8; ++e) {
      const float f = bf2f(in[e]);
      v[e] = (base + e < L) ? f : -1e30f;
      m = fmaxf(m, v[e]);
    }
  } else {
#pragma unroll
    for (int e = 0; e < 8; ++e) v[e] = -1e30f;
  }
#pragma unroll
  for (int o = 32; o > 0; o >>= 1) m = fmaxf(m, __shfl_xor(m, o, 64));
  __shared__ float redm[4], reds[4];
  if (lane == 0) redm[wave] = m;
  __syncthreads();
  m = fmaxf(fmaxf(redm[0], redm[1]), fmaxf(redm[2], redm[3]));

  float s = 0.0f;
#pragma unroll
  for (int e = 0; e < 8; ++e) {
    const float ex = __expf(v[e] - m);       // v==-1e30 -> 0
    v[e] = (base + e < L) ? ex : 0.0f;
    s += v[e];
  }
#pragma unroll
  for (int o = 32; o > 0; o >>= 1) s += __shfl_xor(s, o, 64);
  if (lane == 0) reds[wave] = s;
  __syncthreads();
  s = reds[0] + reds[1] + reds[2] + reds[3];
  const float inv = 1.0f / s;

  if (base < Lw) {
    u16x8 o8;
#pragma unroll
    for (int e = 0; e < 8; ++e) o8[e] = f2bf(v[e] * inv);
    *(u16x8*)(p + base) = o8;
  }
}

extern "C" void kernel_launch(void* const* d_in, const int* in_sizes, int n_in,
                              void* d_out, int out_size, void* d_ws, size_t ws_size,
                              hipStream_t stream)
{
  (void)in_sizes; (void)n_in; (void)out_size; (void)ws_size;
  const int B = 8, T = 2048, C = 1024;
  const int M = B * T;        // 16384
  const int C3 = 3 * C;       // 3072

  // inputs AND output are FP32 (reference dtypes)
  const float* x     = (const float*)d_in[0];
  const float* Wkqv  = (const float*)d_in[1];
  const float* bkqv  = (const float*)d_in[2];
  const float* Wproj = (const float*)d_in[3];
  const float* bproj = (const float*)d_in[4];
  float* out = (float*)d_out;

  // Workspace: 232 MiB footprint. xb dead after GEMM1; ao aliases it.
  char* w = (char*)d_ws;
  u16* xb     = (u16*)w; w += (size_t)M * C * 2;        // 33.5 MB [M][C]  (aliased by ao)
  u16* WkqvT  = (u16*)w; w += (size_t)C3 * C * 2;       //  6.3 MB [3C][C]
  u16* WprojT = (u16*)w; w += (size_t)C * C * 2;        //  2.1 MB [C][C]
  u16* kqv    = (u16*)w; w += (size_t)M * C3 * 2;       // 100.7 MB [M][3C] (v third unused)
  u16* vT     = (u16*)w; w += (size_t)B * C * T * 2;    // 33.5 MB [B][C][T]
  u16* sc     = (u16*)w; w += (size_t)B * T * T * 2;    // 67.1 MB [B][T][T]
  u16* ao     = xb;                                     // alias: lifetimes disjoint

  dim3 tb(32, 8);

  // x -> bf16
  f32_to_bf16<<<(M * C) / 1024, 256, 0, stream>>>(x, xb);

  // weights -> bf16, NT layout
  transpose_f2b<<<dim3(C3 / 32, C / 32, 1), tb, 0, stream>>>(Wkqv, C3, WkqvT, C);
  transpose_f2b<<<dim3(C / 32, C / 32, 1), tb, 0, stream>>>(Wproj, C, WprojT, C);

  // kqv = x @ W_kqv + b_kqv  [M][3C]. mode 3: N fastest -> A-tile L2 reuse;
  // T1 swizzle gives each XCD 8 M-rows x all 12 N (A set = 4 MB = one L2).
  // V third is written TRANSPOSED directly into vT (fused epilogue).
  gemm_nt<u16><<<dim3(C3 / BN, M / BM, 1), 512, 0, stream>>>(
      xb, C, 0, WkqvT, C, 0, kqv, C3, 0, C, bkqv, 1.0f, 3, vT);

  // scores = q @ k^T * (1/sqrt(T)), lower-triangular tiles only
  // (T1 swizzle chunk = 64 blocks = exactly one batch per XCD)
  gemm_nt<u16><<<dim3(T / BM, T / BN, B), 512, 0, stream>>>(
      kqv + C, C3, (long long)T * C3, kqv, C3, (long long)T * C3,
      sc, T, (long long)T * T, C, nullptr, 0.022097086912079608f, 1, nullptr);

  // causal softmax in place
  softmax_causal<<<B * T, 256, 0, stream>>>(sc, T);

  // ao = probs @ v  (NT against vT), K trimmed per tile row; ao aliases xb
  // (T1 swizzle chunk = 32 blocks = one batch per XCD)
  gemm_nt<u16><<<dim3(T / BM, C / BN, B), 512, 0, stream>>>(
      sc, T, (long long)T * T, vT, T, (long long)C * T,
      ao, C, (long long)T * C, T, nullptr, 1.0f, 2, nullptr);

  // out = ao @ W_proj + b_proj   -- FP32 output. mode 3 (grid x=N fastest)
  // so the 4 N-blocks sharing an A-tile are adjacent -> same XCD after T1.
  gemm_nt<float><<<dim3(C / BN, M / BM, 1), 512, 0, stream>>>(
      ao, C, 0, WprojT, C, 0, out, C, 0, C, bproj, 1.0f, 3, nullptr);
}

// Round 8
// 422.534 us; speedup vs baseline: 1.0887x; 1.0887x over previous
//
#include <hip/hip_runtime.h>

typedef unsigned short u16;
typedef __attribute__((ext_vector_type(8))) __bf16 bf16x8;
typedef __attribute__((ext_vector_type(8))) unsigned short u16x8;
typedef __attribute__((ext_vector_type(4))) unsigned short u16x4;
typedef __attribute__((ext_vector_type(4))) float f32x4;

#define BM 256
#define BN 256
#define BK 64   // K-step per LDS buffer; double-buffered (128 KiB total)

__device__ __forceinline__ float bf2f(u16 x) {
  union { unsigned int u; float f; } un;
  un.u = ((unsigned int)x) << 16;
  return un.f;
}

__device__ __forceinline__ u16 f2bf(float f) {
  union { float f; unsigned int u; } un;
  un.f = f;
  unsigned int r = un.u + 0x7fffu + ((un.u >> 16) & 1u);
  return (u16)(r >> 16);
}

__device__ __forceinline__ void cstore(u16* p, float v)   { *p = f2bf(v); }
__device__ __forceinline__ void cstore(float* p, float v) { *p = v; }

// async global->LDS, 16B per lane; lds dst is wave-uniform base (HW adds lane*16B)
__device__ __forceinline__ void async_ld16(const u16* g, u16* l) {
  __builtin_amdgcn_global_load_lds(
      (const __attribute__((address_space(1))) unsigned int*)g,
      (__attribute__((address_space(3))) unsigned int*)l, 16, 0, 0);
}

__device__ __forceinline__ bf16x8 ldfrag(const u16* p) {
  union { u16x8 u; bf16x8 b; } c;
  c.u = *(const u16x8*)p;
  return c.b;
}

// ---------------- fp32 -> bf16 elementwise (x), 4 elems/thread ----------------
__global__ __launch_bounds__(256)
void f32_to_bf16(const float* __restrict__ s, u16* __restrict__ d)
{
  const int i = blockIdx.x * 256 + threadIdx.x;
  const float4 v = ((const float4*)s)[i];
  u16x4 o;
  o.x = f2bf(v.x); o.y = f2bf(v.y); o.z = f2bf(v.z); o.w = f2bf(v.w);
  ((u16x4*)d)[i] = o;
}

// ---------------- fp32 [R][CC] -> bf16 transposed [CC][R] ----------------
__global__ __launch_bounds__(256)
void transpose_f2b(const float* __restrict__ src, int sld,
                   u16* __restrict__ dst, int dld)
{
  __shared__ float tile[32][33];
  const int c0 = blockIdx.x * 32;
  const int r0 = blockIdx.y * 32;
  const int tx = threadIdx.x;   // 0..31
  const int ty = threadIdx.y;   // 0..7
#pragma unroll
  for (int i = ty; i < 32; i += 8)
    tile[i][tx] = src[(long long)(r0 + i) * sld + c0 + tx];
  __syncthreads();
#pragma unroll
  for (int i = ty; i < 32; i += 8)
    dst[(long long)(c0 + i) * dld + r0 + tx] = f2bf(tile[tx][i]);
}

// C[M][N] = A[M][K] * Bt[N][K]^T  (NT GEMM), bf16 in, fp32 accum, OT out.
// 256x256 tile, BK=64 double-buffered (128 KiB LDS), 8 waves (2M x 4N,
// 128x64 out/wave), 4 phases/K-tile, 16 MFMA each. K-loop structure = r6
// (best measured): register-pipelined frag reads (P1 slot issues P1+P2
// frags, P3 slot issues P3+P4), deep-slack staging:
//   P1 top: issue B01,B23,A01 of tile j+1   (6 loads)
//   P3 top: issue A23 of tile j+1            (2 loads)
//   end-P2: vmcnt(6) -> A23 of tile j landed (3-phase slack)
//   end-P4: vmcnt(2) -> B01,B23,A01 of tile j+1 landed (3-phase slack)
// LDS bank swizzle (slot ^= row&7 on 16B slots), both-sides rule.
// T1 XCD swizzle: flat block id chunked (bijective, all grids %8==0).
// r8 NEW: coalesced u16 epilogue — after the K-loop the LDS is dead; each
// wave stages its 128x64 bf16 tile (two 64-row halves, private region,
// row stride 144 B) then stores 16 B/lane/inst: 16 global_store_dwordx4
// per thread replaces 128 scalar 2B stores. Read-back = 8 words/bank
// (conflict-free minimum); staging writes <=4-way.
// mode 0: plain; mode 1: causal skip; mode 2: K trimmed to (bx+1)*BM;
// mode 3: plain, swapped block decode. kEnd must be a multiple of 64.
// vdst != nullptr: blocks with N-base >= 2048 write u16 output TRANSPOSED
// into vdst[b][col-2048][row%2048] (fused V-transpose for the kqv GEMM).
template <typename OT>
__global__ __launch_bounds__(512, 2)
void gemm_nt(const u16* __restrict__ A, int lda, long long sA,
             const u16* __restrict__ Bt, int ldb, long long sB,
             OT* __restrict__ Cp, int ldc, long long sC,
             int K, const float* __restrict__ bias, float scale, int mode,
             u16* __restrict__ vdst)
{
  // ---- T1: XCD-chunked bijective block swizzle (requires nwg % 8 == 0) ----
  const int gx = gridDim.x, gy = gridDim.y;
  const int nwg  = gx * gy * gridDim.z;
  const int flat = blockIdx.x + gx * (blockIdx.y + gy * blockIdx.z);
  const int qch  = nwg >> 3;
  const int swzf = (flat & 7) * qch + (flat >> 3);
  int bx = swzf % gx;
  const int rem = swzf / gx;
  int by = rem % gy;
  const int bz = rem / gy;
  if (mode == 3) { const int t2 = bx; bx = by; by = t2; }
  if (mode == 1 && by > bx) return;
  A  += (long long)bz * sA;
  Bt += (long long)bz * sB;
  Cp += (long long)bz * sC;
  int kEnd = K;
  if (mode == 2) { int ke = (bx + 1) * BM; kEnd = ke < K ? ke : K; }

  __shared__ __align__(16) u16 As[2][BM * BK];
  __shared__ __align__(16) u16 Bs[2][BM * BK];

  const int tid  = threadIdx.x;
  const int wave = tid >> 6;      // 0..7
  const int lane = tid & 63;
  const int l16  = lane & 15;
  const int quad = lane >> 4;     // 0..3
  const int wm = wave >> 2;       // 0..1 -> rows wm*128..+127
  const int wn = wave & 3;        // 0..3 -> cols wn*64..+63

  // ds_read slot (16B units) = (kk*4+quad) ^ (row&7); row&7 == l16&7.
  const int sk0 = ((quad    ) ^ (l16 & 7)) * 8;   // kk = 0
  const int sk1 = ((quad + 4) ^ (l16 & 7)) * 8;   // kk = 1
  const int arow = wm * 128 + l16;
  const int brow = wn * 64  + l16;

  // staging: chunk = 1 KiB = 8 rows x 64 cols; lane l -> row chunk*8+(l>>3),
  // slot l&7; source col = swizzle-inverse ((l&7)^(l>>3))*8 elems.
  const int srow8 = lane >> 3;
  const int sx    = ((lane & 7) ^ srow8) * 8;

  // wave w stages B chunks {4w..4w+3}; A chunks: first-half {f0,f0+1},
  // second-half {f0+8,f0+9}.
  const int f0 = (wave < 4) ? (2 * wave) : (16 + 2 * (wave - 4));
  const int aCh[4] = { f0, f0 + 1, f0 + 8, f0 + 9 };

  const u16* Bgp[4];
#pragma unroll
  for (int p = 0; p < 4; ++p)
    Bgp[p] = Bt + (long long)(by * BN + (4 * wave + p) * 8 + srow8) * ldb + sx;
  const u16* Agp[4];
#pragma unroll
  for (int q = 0; q < 4; ++q)
    Agp[q] = A + (long long)(bx * BM + aCh[q] * 8 + srow8) * lda + sx;

  f32x4 zero4;
  zero4.x = zero4.y = zero4.z = zero4.w = 0.0f;
  f32x4 acc[8][4];
#pragma unroll
  for (int i = 0; i < 8; ++i)
#pragma unroll
    for (int j = 0; j < 4; ++j) acc[i][j] = zero4;

  const int nt = kEnd / BK;

  // prologue: tile 0 -> buf 0; order B0-3, A01, A23 (A23 newest — matches
  // steady-state invariant); vmcnt(2) leaves A23 in flight (landed by
  // end-P2's vmcnt(6)).
#pragma unroll
  for (int p = 0; p < 4; ++p) async_ld16(Bgp[p], &Bs[0][(4 * wave + p) * 512]);
#pragma unroll
  for (int q = 0; q < 4; ++q) async_ld16(Agp[q], &As[0][aCh[q] * 512]);
  asm volatile("s_waitcnt vmcnt(2)" ::: "memory");
  __builtin_amdgcn_s_barrier();

  for (int j = 0; j < nt; ++j) {
    const int cur = j & 1;
    const int nxt = cur ^ 1;
    const bool pf = (j + 1 < nt);
    const int ko = (j + 1) * BK;

    bf16x8 bv0[4], bv1[4], av0[4], av1[4];

    // ---- P1 slot: issue R1+R2 frags; stage B01,B23,A01 of tile j+1 ----
#pragma unroll
    for (int n = 0; n < 4; ++n) bv0[n] = ldfrag(&Bs[cur][(brow + n * 16) * BK + sk0]);
#pragma unroll
    for (int i = 0; i < 4; ++i) av0[i] = ldfrag(&As[cur][(arow + i * 16) * BK + sk0]);
#pragma unroll
    for (int n = 0; n < 4; ++n) bv1[n] = ldfrag(&Bs[cur][(brow + n * 16) * BK + sk1]);
#pragma unroll
    for (int i = 0; i < 4; ++i) av1[i] = ldfrag(&As[cur][(arow + i * 16) * BK + sk1]);
    if (pf) {
      async_ld16(Bgp[0] + ko, &Bs[nxt][(4 * wave + 0) * 512]);
      async_ld16(Bgp[1] + ko, &Bs[nxt][(4 * wave + 1) * 512]);
      async_ld16(Bgp[2] + ko, &Bs[nxt][(4 * wave + 2) * 512]);
      async_ld16(Bgp[3] + ko, &Bs[nxt][(4 * wave + 3) * 512]);
      async_ld16(Agp[0] + ko, &As[nxt][aCh[0] * 512]);
      async_ld16(Agp[1] + ko, &As[nxt][aCh[1] * 512]);
    }
    asm volatile("" ::: "memory");
    __builtin_amdgcn_s_barrier();
    __builtin_amdgcn_s_setprio(1);
#pragma unroll
    for (int i = 0; i < 4; ++i)
#pragma unroll
      for (int n = 0; n < 4; ++n)
        acc[i][n] = __builtin_amdgcn_mfma_f32_16x16x32_bf16(av0[i], bv0[n], acc[i][n], 0, 0, 0);
    __builtin_amdgcn_s_setprio(0);
    asm volatile("" ::: "memory");
    __builtin_amdgcn_s_barrier();

    // ---- P2 slot: no new reads, no new stages ----
    __builtin_amdgcn_s_setprio(1);
#pragma unroll
    for (int i = 0; i < 4; ++i)
#pragma unroll
      for (int n = 0; n < 4; ++n)
        acc[i][n] = __builtin_amdgcn_mfma_f32_16x16x32_bf16(av1[i], bv1[n], acc[i][n], 0, 0, 0);
    __builtin_amdgcn_s_setprio(0);
    // A23 of tile j must land before P3-slot reads (issued P3 of j-1,
    // 3-phase slack). The 6 tile-j+1 loads issued at P1 stay in flight.
    if (pf) asm volatile("s_waitcnt vmcnt(6)" ::: "memory");
    else    asm volatile("s_waitcnt vmcnt(0)" ::: "memory");
    __builtin_amdgcn_s_barrier();

    // ---- P3 slot: issue R3+R4 frags; stage A23 of tile j+1 ----
#pragma unroll
    for (int i = 0; i < 4; ++i) av0[i] = ldfrag(&As[cur][(arow + (i + 4) * 16) * BK + sk0]);
#pragma unroll
    for (int i = 0; i < 4; ++i) av1[i] = ldfrag(&As[cur][(arow + (i + 4) * 16) * BK + sk1]);
    if (pf) {
      async_ld16(Agp[2] + ko, &As[nxt][aCh[2] * 512]);
      async_ld16(Agp[3] + ko, &As[nxt][aCh[3] * 512]);
    }
    asm volatile("" ::: "memory");
    __builtin_amdgcn_s_barrier();
    __builtin_amdgcn_s_setprio(1);
#pragma unroll
    for (int i = 0; i < 4; ++i)
#pragma unroll
      for (int n = 0; n < 4; ++n)
        acc[i + 4][n] = __builtin_amdgcn_mfma_f32_16x16x32_bf16(av0[i], bv0[n], acc[i + 4][n], 0, 0, 0);
    __builtin_amdgcn_s_setprio(0);
    asm volatile("" ::: "memory");
    __builtin_amdgcn_s_barrier();

    // ---- P4 slot: no new reads, no new stages ----
    __builtin_amdgcn_s_setprio(1);
#pragma unroll
    for (int i = 0; i < 4; ++i)
#pragma unroll
      for (int n = 0; n < 4; ++n)
        acc[i + 4][n] = __builtin_amdgcn_mfma_f32_16x16x32_bf16(av1[i], bv1[n], acc[i + 4][n], 0, 0, 0);
    __builtin_amdgcn_s_setprio(0);
    // B01,B23,A01 of tile j+1 must land before next P1-slot reads (issued at
    // P1 of this tile, 3-phase slack). A23 (2 newest) stays in flight.
    if (pf) asm volatile("s_waitcnt vmcnt(2)" ::: "memory");
    __builtin_amdgcn_s_barrier();
  }

  // ---- epilogue: C/D layout col = lane&15, row = quad*4 + reg (m89/m91) ----
  const bool isv = (vdst != nullptr) && (by * BN >= 2048);
  if (isv) {
    // fused V-transpose: write vdst[b][vc][t], b = batch, t = row % 2048.
    // Lane's 4 acc rows = 4 consecutive t at fixed vc -> one 8 B store;
    // quads fill 32 B contiguous -> sectors complete in L2.
    const int b  = bx >> 3;                       // 2048/BM = 8 blocks/batch
    const int t0 = (bx & 7) * BM + wm * 128 + quad * 4;
    u16* vb = vdst + (long long)b * 1024 * 2048;  // C * T
    const int vc0 = by * BN - 2048 + wn * 64 + l16;
#pragma unroll
    for (int j = 0; j < 4; ++j) {
      const int vc = vc0 + j * 16;
      const float bval = bias ? bias[2048 + vc] : 0.0f;
#pragma unroll
      for (int i = 0; i < 8; ++i) {
        u16x4 o;
#pragma unroll
        for (int r = 0; r < 4; ++r) o[r] = f2bf(acc[i][j][r] * scale + bval);
        *(u16x4*)(vb + (long long)vc * 2048 + t0 + i * 16) = o;
      }
    }
  } else if constexpr (sizeof(OT) == 2) {
    // r8: coalesced u16 C-store via LDS round-trip. After the loop's final
    // barrier all LDS reads/writes are retired -> As/Bs reusable as scratch.
    // Per-wave private region: 64 rows x 72 u16 (144 B stride), 9216 B;
    // waves 0-3 in As, waves 4-7 in Bs.
    u16* wb = (wave < 4) ? ((u16*)As + (wave & 3) * 4608)
                         : ((u16*)Bs + (wave & 3) * 4608);
    const long long rowg0 = (long long)bx * BM + wm * 128;
    const int colg0 = by * BN + wn * 64;
    float bv4[4];
#pragma unroll
    for (int j = 0; j < 4; ++j)
      bv4[j] = bias ? bias[colg0 + l16 + 16 * j] : 0.0f;
#pragma unroll
    for (int h = 0; h < 2; ++h) {
      // stage half-tile h (rows h*64 .. h*64+63 of the wave's 128)
#pragma unroll
      for (int ip = 0; ip < 4; ++ip) {
        const int ii = h * 4 + ip;
#pragma unroll
        for (int j = 0; j < 4; ++j) {
#pragma unroll
          for (int r = 0; r < 4; ++r) {
            const int rl = ip * 16 + quad * 4 + r;   // 0..63
            wb[rl * 72 + l16 + 16 * j] = f2bf(acc[ii][j][r] * scale + bv4[j]);
          }
        }
      }
      // read back linearly (8 rows x 64 cols per pass) and store 16 B/lane
#pragma unroll
      for (int t = 0; t < 8; ++t) {
        const int rl = t * 8 + (lane >> 3);
        const u16x8 v = *(const u16x8*)(wb + rl * 72 + (lane & 7) * 8);
        *(u16x8*)(&Cp[(rowg0 + h * 64 + rl) * (long long)ldc + colg0 + (lane & 7) * 8]) = v;
      }
    }
  } else {
    // fp32 path (proj): 16 lanes x 4 B = 64 B contiguous per row — already
    // sector-aligned; keep scalar stores.
    const long long row0 = (long long)bx * BM + wm * 128 + quad * 4;
    const int col0 = by * BN + wn * 64 + l16;
#pragma unroll
    for (int j = 0; j < 4; ++j) {
      const int col = col0 + j * 16;
      const float bval = bias ? bias[col] : 0.0f;
#pragma unroll
      for (int i = 0; i < 8; ++i) {
#pragma unroll
        for (int r = 0; r < 4; ++r) {
          const long long row = row0 + i * 16 + r;
          cstore(&Cp[row * ldc + col], acc[i][j][r] * scale + bval);
        }
      }
    }
  }
}

// causal softmax over one row of [T] bf16 scores, in place.
// Thread t owns elements [8t, 8t+8). Reads AND writes only [0, Lw),
// Lw = ceil(L/256)*256 — exactly the range the K-trimmed PV GEMM consumes.
// requires T == 2048
__global__ __launch_bounds__(256)
void softmax_causal(u16* __restrict__ sc, int T)
{
  const int row = blockIdx.x;       // z*T + t
  const int t = row & (T - 1);
  u16* p = sc + (long long)row * T;
  const int L  = t + 1;
  const int Lw = ((t >> 8) + 1) << 8;   // 256-aligned for BM=256 PV trim
  const int tid = threadIdx.x;
  const int lane = tid & 63;
  const int wave = tid >> 6;
  const int base = tid * 8;

  float v[8];
  float m = -1e30f;
  if (base < Lw) {
    const u16x8 in = *(const u16x8*)(p + base);
#pragma unroll
    for (int e = 0; e < 8; ++e) {
      const float f = bf2f(in[e]);
      v[e] = (base + e < L) ? f : -1e30f;
      m = fmaxf(m, v[e]);
    }
  } else {
#pragma unroll
    for (int e = 0; e < 8; ++e) v[e] = -1e30f;
  }
#pragma unroll
  for (int o = 32; o > 0; o >>= 1) m = fmaxf(m, __shfl_xor(m, o, 64));
  __shared__ float redm[4], reds[4];
  if (lane == 0) redm[wave] = m;
  __syncthreads();
  m = fmaxf(fmaxf(redm[0], redm[1]), fmaxf(redm[2], redm[3]));

  float s = 0.0f;
#pragma unroll
  for (int e = 0; e < 8; ++e) {
    const float ex = __expf(v[e] - m);       // v==-1e30 -> 0
    v[e] = (base + e < L) ? ex : 0.0f;
    s += v[e];
  }
#pragma unroll
  for (int o = 32; o > 0; o >>= 1) s += __shfl_xor(s, o, 64);
  if (lane == 0) reds[wave] = s;
  __syncthreads();
  s = reds[0] + reds[1] + reds[2] + reds[3];
  const float inv = 1.0f / s;

  if (base < Lw) {
    u16x8 o8;
#pragma unroll
    for (int e = 0; e < 8; ++e) o8[e] = f2bf(v[e] * inv);
    *(u16x8*)(p + base) = o8;
  }
}

extern "C" void kernel_launch(void* const* d_in, const int* in_sizes, int n_in,
                              void* d_out, int out_size, void* d_ws, size_t ws_size,
                              hipStream_t stream)
{
  (void)in_sizes; (void)n_in; (void)out_size; (void)ws_size;
  const int B = 8, T = 2048, C = 1024;
  const int M = B * T;        // 16384
  const int C3 = 3 * C;       // 3072

  // inputs AND output are FP32 (reference dtypes)
  const float* x     = (const float*)d_in[0];
  const float* Wkqv  = (const float*)d_in[1];
  const float* bkqv  = (const float*)d_in[2];
  const float* Wproj = (const float*)d_in[3];
  const float* bproj = (const float*)d_in[4];
  float* out = (float*)d_out;

  // Workspace: 232 MiB footprint. xb dead after GEMM1; ao aliases it.
  char* w = (char*)d_ws;
  u16* xb     = (u16*)w; w += (size_t)M * C * 2;        // 33.5 MB [M][C]  (aliased by ao)
  u16* WkqvT  = (u16*)w; w += (size_t)C3 * C * 2;       //  6.3 MB [3C][C]
  u16* WprojT = (u16*)w; w += (size_t)C * C * 2;        //  2.1 MB [C][C]
  u16* kqv    = (u16*)w; w += (size_t)M * C3 * 2;       // 100.7 MB [M][3C] (v third unused)
  u16* vT     = (u16*)w; w += (size_t)B * C * T * 2;    // 33.5 MB [B][C][T]
  u16* sc     = (u16*)w; w += (size_t)B * T * T * 2;    // 67.1 MB [B][T][T]
  u16* ao     = xb;                                     // alias: lifetimes disjoint

  dim3 tb(32, 8);

  // x -> bf16
  f32_to_bf16<<<(M * C) / 1024, 256, 0, stream>>>(x, xb);

  // weights -> bf16, NT layout
  transpose_f2b<<<dim3(C3 / 32, C / 32, 1), tb, 0, stream>>>(Wkqv, C3, WkqvT, C);
  transpose_f2b<<<dim3(C / 32, C / 32, 1), tb, 0, stream>>>(Wproj, C, WprojT, C);

  // kqv = x @ W_kqv + b_kqv  [M][3C]. mode 3: N fastest -> A-tile L2 reuse;
  // T1 swizzle gives each XCD 8 M-rows x all 12 N (A set = 4 MB = one L2).
  // V third is written TRANSPOSED directly into vT (fused epilogue).
  gemm_nt<u16><<<dim3(C3 / BN, M / BM, 1), 512, 0, stream>>>(
      xb, C, 0, WkqvT, C, 0, kqv, C3, 0, C, bkqv, 1.0f, 3, vT);

  // scores = q @ k^T * (1/sqrt(T)), lower-triangular tiles only
  // (T1 swizzle chunk = 64 blocks = exactly one batch per XCD)
  gemm_nt<u16><<<dim3(T / BM, T / BN, B), 512, 0, stream>>>(
      kqv + C, C3, (long long)T * C3, kqv, C3, (long long)T * C3,
      sc, T, (long long)T * T, C, nullptr, 0.022097086912079608f, 1, nullptr);

  // causal softmax in place
  softmax_causal<<<B * T, 256, 0, stream>>>(sc, T);

  // ao = probs @ v  (NT against vT), K trimmed per tile row; ao aliases xb
  // (T1 swizzle chunk = 32 blocks = one batch per XCD)
  gemm_nt<u16><<<dim3(T / BM, C / BN, B), 512, 0, stream>>>(
      sc, T, (long long)T * T, vT, T, (long long)C * T,
      ao, C, (long long)T * C, T, nullptr, 1.0f, 2, nullptr);

  // out = ao @ W_proj + b_proj   -- FP32 output. mode 3 (grid x=N fastest)
  // so the 4 N-blocks sharing an A-tile are adjacent -> same XCD after T1.
  gemm_nt<float><<<dim3(C / BN, M / BM, 1), 512, 0, stream>>>(
      ao, C, 0, WprojT, C, 0, out, C, 0, C, bproj, 1.0f, 3, nullptr);
}